// Round 1
// baseline (244.968 us; speedup 1.0000x reference)
//
#include <hip/hip_runtime.h>
#include <cstdint>
#include <cmath>

#define NROWS 8192
#define KDIM  512
#define T_INV 10.0f

typedef __bf16 bf16x8 __attribute__((ext_vector_type(8)));
typedef float  f32x4  __attribute__((ext_vector_type(4)));
typedef unsigned short u16;

#define AS1(p) ((const __attribute__((address_space(1))) void*)(p))
#define AS3(p) ((__attribute__((address_space(3))) void*)(p))

// round-to-nearest-even fp32 -> bf16 bits (inputs finite, no NaN handling needed)
__device__ __forceinline__ u16 f2bf(float x) {
    union { float f; unsigned u; } c; c.f = x;
    unsigned u = c.u;
    u += 0x7fffu + ((u >> 16) & 1u);
    return (u16)(u >> 16);
}

// --- Kernel 1: row L2-normalize fp32 -> bf16, zi rows [0,8192), zj rows [8192,16384) ---
__global__ __launch_bounds__(256) void nrm_kernel(const float* __restrict__ zi,
                                                  const float* __restrict__ zj,
                                                  u16* __restrict__ out) {
    const int wave = threadIdx.x >> 6;
    const int lane = threadIdx.x & 63;
    const int row  = blockIdx.x * 4 + wave;            // 0..16383
    const float* src = (row < NROWS) ? zi + (size_t)row * KDIM
                                     : zj + (size_t)(row - NROWS) * KDIM;
    float4 a = ((const float4*)src)[lane];
    float4 b = ((const float4*)src)[lane + 64];
    float ss = a.x*a.x + a.y*a.y + a.z*a.z + a.w*a.w
             + b.x*b.x + b.y*b.y + b.z*b.z + b.w*b.w;
    #pragma unroll
    for (int off = 32; off >= 1; off >>= 1) ss += __shfl_xor(ss, off, 64);
    const float inv = 1.0f / fmaxf(sqrtf(ss), 1e-12f);
    ushort4 pa, pb;
    pa.x = f2bf(a.x * inv); pa.y = f2bf(a.y * inv);
    pa.z = f2bf(a.z * inv); pa.w = f2bf(a.w * inv);
    pb.x = f2bf(b.x * inv); pb.y = f2bf(b.y * inv);
    pb.z = f2bf(b.z * inv); pb.w = f2bf(b.w * inv);
    ushort4* dst = (ushort4*)(out + (size_t)row * KDIM);
    dst[lane]      = pa;
    dst[lane + 64] = pb;
}

// --- Kernel 2: init accumulators (capture-safe zeroing; ws is poisoned 0xAA each call) ---
__global__ void init_acc(double* acc) { acc[0] = 0.0; acc[1] = 0.0; }

// --- Kernel 3: fused A*B^T -> exp(10*dot) -> global sum.
// A = normalized zi [8192][512] bf16; B = normalized [16384][512] (zi then zj).
// Block computes a 128x128 tile; never materializes C.
__global__ __launch_bounds__(256) void gemm_exp_reduce(const u16* __restrict__ A,
                                                       const u16* __restrict__ B,
                                                       double* __restrict__ acc) {
    __shared__ u16 lA[128 * 32];   // 8 KB, row-major [128][32]
    __shared__ u16 lB[128 * 32];   // 8 KB
    __shared__ float red[4];

    const int tid  = threadIdx.x;
    const int lane = tid & 63;
    const int wave = tid >> 6;
    const int m0   = blockIdx.y * 128;
    const int n0   = blockIdx.x * 128;
    const int wm   = (wave >> 1) * 64;   // wave row offset in tile
    const int wn   = (wave & 1) * 64;    // wave col offset in tile

    f32x4 accf[4][4];
    #pragma unroll
    for (int i = 0; i < 4; ++i)
        #pragma unroll
        for (int j = 0; j < 4; ++j)
            accf[i][j] = (f32x4){0.f, 0.f, 0.f, 0.f};

    // staging: thread stages 16B (8 bf16) at tile row (tid>>2)+i*64, k-chunk (tid&3)*8
    const u16* gA = A + (size_t)(m0 + (tid >> 2)) * KDIM + (tid & 3) * 8;
    const u16* gB = B + (size_t)(n0 + (tid >> 2)) * KDIM + (tid & 3) * 8;

    const int frow = lane & 15;        // fragment row/col within 16
    const int fk   = (lane >> 4) * 8;  // fragment k offset

    for (int k0 = 0; k0 < KDIM; k0 += 32) {
        __syncthreads();   // previous iteration's ds_reads done before overwrite
        #pragma unroll
        for (int i = 0; i < 2; ++i) {
            __builtin_amdgcn_global_load_lds(AS1(gA + k0 + (size_t)i * 64 * KDIM),
                                             AS3(&lA[tid * 8 + i * 2048]), 16, 0, 0);
            __builtin_amdgcn_global_load_lds(AS1(gB + k0 + (size_t)i * 64 * KDIM),
                                             AS3(&lB[tid * 8 + i * 2048]), 16, 0, 0);
        }
        __syncthreads();   // vmcnt(0) drain + barrier: LDS tiles ready

        bf16x8 af[4], bfr[4];
        #pragma unroll
        for (int mi = 0; mi < 4; ++mi)
            af[mi] = *(const bf16x8*)&lA[(wm + mi * 16 + frow) * 32 + fk];
        #pragma unroll
        for (int ni = 0; ni < 4; ++ni)
            bfr[ni] = *(const bf16x8*)&lB[(wn + ni * 16 + frow) * 32 + fk];
        #pragma unroll
        for (int mi = 0; mi < 4; ++mi)
            #pragma unroll
            for (int ni = 0; ni < 4; ++ni)
                accf[mi][ni] = __builtin_amdgcn_mfma_f32_16x16x32_bf16(
                    af[mi], bfr[ni], accf[mi][ni], 0, 0, 0);
    }

    // epilogue: exp(10*dot) and reduce — C/D layout irrelevant, we sum everything
    float part = 0.f;
    #pragma unroll
    for (int mi = 0; mi < 4; ++mi)
        #pragma unroll
        for (int ni = 0; ni < 4; ++ni)
            #pragma unroll
            for (int r = 0; r < 4; ++r)
                part += __expf(accf[mi][ni][r] * T_INV);

    #pragma unroll
    for (int off = 32; off >= 1; off >>= 1) part += __shfl_xor(part, off, 64);
    if (lane == 0) red[wave] = part;
    __syncthreads();
    if (tid == 0) {
        double s = (double)red[0] + (double)red[1] + (double)red[2] + (double)red[3];
        atomicAdd(&acc[(blockIdx.x < 64) ? 0 : 1], s);   // n-tile in zi region -> pos
    }
}

// --- Kernel 4: loss = -log(pos/(pos+neg)) = log1p(neg/pos) ---
__global__ void finalize(const double* __restrict__ acc, float* __restrict__ out) {
    out[0] = (float)log1p(acc[1] / acc[0]);
}

extern "C" void kernel_launch(void* const* d_in, const int* in_sizes, int n_in,
                              void* d_out, int out_size, void* d_ws, size_t ws_size,
                              hipStream_t stream) {
    const float* zi = (const float*)d_in[0];
    const float* zj = (const float*)d_in[1];
    u16* nrm = (u16*)d_ws;                                    // [16384][512] bf16 = 16 MB
    double* acc = (double*)((char*)d_ws + (size_t)16384 * 512 * 2);

    nrm_kernel<<<4096, 256, 0, stream>>>(zi, zj, nrm);
    init_acc<<<1, 1, 0, stream>>>(acc);
    dim3 grid(128, 64);   // x: 16384/128 n-tiles, y: 8192/128 m-tiles
    gemm_exp_reduce<<<grid, 256, 0, stream>>>(nrm, nrm, acc);
    finalize<<<1, 1, 0, stream>>>(acc, (float*)d_out);
}

// Round 2
// 187.889 us; speedup vs baseline: 1.3038x; 1.3038x over previous
//
#include <hip/hip_runtime.h>
#include <cstdint>
#include <cmath>

#define NROWS 8192
#define KDIM  512            // elements; also bytes/row in fp8
#define T_INV 10.0f

typedef int    i32x8  __attribute__((ext_vector_type(8)));
typedef float  f32x16 __attribute__((ext_vector_type(16)));
typedef unsigned char u8;

#define AS1(p) ((const __attribute__((address_space(1))) void*)(p))
#define AS3(p) ((__attribute__((address_space(3))) void*)(p))

// --- Kernel 1: row L2-normalize fp32 -> fp8 e4m3 (OCP, HW cvt), one wave/row.
// zi rows [0,8192), zj rows [8192,16384). Also zeroes the accumulators.
__global__ __launch_bounds__(256) void nrm_kernel(const float* __restrict__ zi,
                                                  const float* __restrict__ zj,
                                                  u8* __restrict__ out,
                                                  double* __restrict__ acc) {
    if (blockIdx.x == 0 && threadIdx.x == 0) { acc[0] = 0.0; acc[1] = 0.0; }
    const int wave = threadIdx.x >> 6;
    const int lane = threadIdx.x & 63;
    const int row  = blockIdx.x * 4 + wave;            // 0..16383
    const float* src = (row < NROWS) ? zi + (size_t)row * KDIM
                                     : zj + (size_t)(row - NROWS) * KDIM;
    float4 a = ((const float4*)src)[lane];        // elements 4*lane .. 4*lane+3
    float4 b = ((const float4*)src)[lane + 64];   // elements 4*(lane+64) ..
    float ss = a.x*a.x + a.y*a.y + a.z*a.z + a.w*a.w
             + b.x*b.x + b.y*b.y + b.z*b.z + b.w*b.w;
    #pragma unroll
    for (int off = 32; off >= 1; off >>= 1) ss += __shfl_xor(ss, off, 64);
    const float inv = 1.0f / fmaxf(sqrtf(ss), 1e-12f);
    int p0 = 0, p1 = 0;
    p0 = __builtin_amdgcn_cvt_pk_fp8_f32(a.x * inv, a.y * inv, p0, false); // bytes 0,1
    p0 = __builtin_amdgcn_cvt_pk_fp8_f32(a.z * inv, a.w * inv, p0, true);  // bytes 2,3
    p1 = __builtin_amdgcn_cvt_pk_fp8_f32(b.x * inv, b.y * inv, p1, false);
    p1 = __builtin_amdgcn_cvt_pk_fp8_f32(b.z * inv, b.w * inv, p1, true);
    int* dst = (int*)(out + (size_t)row * KDIM);
    dst[lane]      = p0;   // bytes 4*lane..4*lane+3  == elements 4*lane..
    dst[lane + 64] = p1;
}

// --- Kernel 2: fused MX-fp8 A*B^T -> exp(10*dot) -> global sum.
// A = normalized zi [8192][512] fp8; B = normalized [16384][512] (zi then zj).
// Block = 128x128 tile, 4 waves in 2x2, each wave 64x64 via 2x2 of 32x32x64 frags.
// Diagonal elements of the pos region are SKIPPED (added exactly in finalize).
__global__ __launch_bounds__(256) void gemm_exp_reduce(const u8* __restrict__ A,
                                                       const u8* __restrict__ B,
                                                       double* __restrict__ acc) {
    __shared__ u8 lA[128 * 64];   // 8 KB, row-major [128 rows][64 k-bytes]
    __shared__ u8 lB[128 * 64];   // 8 KB
    __shared__ float red[4];

    const int tid  = threadIdx.x;
    const int lane = tid & 63;
    const int wave = tid >> 6;
    const int m0   = blockIdx.y * 128;
    const int n0   = blockIdx.x * 128;
    const int wm   = (wave >> 1) * 64;
    const int wn   = (wave & 1) * 64;

    f32x16 accf[2][2];
    #pragma unroll
    for (int i = 0; i < 2; ++i)
        #pragma unroll
        for (int j = 0; j < 2; ++j)
            #pragma unroll
            for (int r = 0; r < 16; ++r)
                accf[i][j][r] = 0.f;

    // staging: wave w, chunk c covers LDS [w*2048 + c*1024, +1024) = rows
    // w*32+c*16 .. +16, 64 B/row. lane writes 16B at base + lane*16 (HW rule).
    const u8* gA0 = A + (size_t)(m0 + wave * 32 + (lane >> 2)) * KDIM + (lane & 3) * 16;
    const u8* gB0 = B + (size_t)(n0 + wave * 32 + (lane >> 2)) * KDIM + (lane & 3) * 16;
    u8* lAd = &lA[wave * 2048 + lane * 16];
    u8* lBd = &lB[wave * 2048 + lane * 16];

    const int arow = lane & 31;          // operand row within 32 (all 32x32 MFMAs)
    const int kh   = (lane >> 5) * 32;   // k-half byte offset within 64-byte row

    for (int k0 = 0; k0 < KDIM; k0 += 64) {
        __syncthreads();   // previous iteration's ds_reads done before overwrite
        #pragma unroll
        for (int c = 0; c < 2; ++c) {
            __builtin_amdgcn_global_load_lds(AS1(gA0 + k0 + (size_t)c * 16 * KDIM),
                                             AS3(lAd + c * 1024), 16, 0, 0);
            __builtin_amdgcn_global_load_lds(AS1(gB0 + k0 + (size_t)c * 16 * KDIM),
                                             AS3(lBd + c * 1024), 16, 0, 0);
        }
        __syncthreads();   // vmcnt drain + barrier: tiles ready

        i32x8 af[2], bfr[2];
        #pragma unroll
        for (int mi = 0; mi < 2; ++mi)
            af[mi] = *(const i32x8*)&lA[(wm + mi * 32 + arow) * 64 + kh];
        #pragma unroll
        for (int ni = 0; ni < 2; ++ni)
            bfr[ni] = *(const i32x8*)&lB[(wn + ni * 32 + arow) * 64 + kh];
        #pragma unroll
        for (int mi = 0; mi < 2; ++mi)
            #pragma unroll
            for (int ni = 0; ni < 2; ++ni)
                accf[mi][ni] = __builtin_amdgcn_mfma_scale_f32_32x32x64_f8f6f4(
                    af[mi], bfr[ni], accf[mi][ni],
                    0, 0,                 // cbsz=fp8(e4m3), blgp=fp8(e4m3)
                    0, 0x7f7f7f7f,        // scale_a: every byte = 2^0
                    0, 0x7f7f7f7f);       // scale_b
    }

    // epilogue: exp(10*dot), skipping pos-region diagonal (only in bx==by tiles)
    float part = 0.f;
    const bool diagblk = (blockIdx.x == (unsigned)blockIdx.y);  // implies pos region
    if (diagblk) {
        #pragma unroll
        for (int mi = 0; mi < 2; ++mi)
            #pragma unroll
            for (int ni = 0; ni < 2; ++ni)
                #pragma unroll
                for (int r = 0; r < 16; ++r) {
                    // C/D 32x32: col=lane&31, row=(r&3)+8*(r>>2)+4*(lane>>5)
                    int rr = wm + mi * 32 + ((r & 3) + 8 * (r >> 2) + 4 * (lane >> 5));
                    int cc = wn + ni * 32 + (lane & 31);
                    if (rr != cc) part += __expf(accf[mi][ni][r] * T_INV);
                }
    } else {
        #pragma unroll
        for (int mi = 0; mi < 2; ++mi)
            #pragma unroll
            for (int ni = 0; ni < 2; ++ni)
                #pragma unroll
                for (int r = 0; r < 16; ++r)
                    part += __expf(accf[mi][ni][r] * T_INV);
    }

    #pragma unroll
    for (int off = 32; off >= 1; off >>= 1) part += __shfl_xor(part, off, 64);
    if (lane == 0) red[wave] = part;
    __syncthreads();
    if (tid == 0) {
        double s = (double)red[0] + (double)red[1] + (double)red[2] + (double)red[3];
        atomicAdd(&acc[(blockIdx.x < 64) ? 0 : 1], s);   // n-tile in zi region -> pos
    }
}

// --- Kernel 3: loss = log1p(neg / pos), pos += exact diagonal 8192*e^10 ---
__global__ void finalize(const double* __restrict__ acc, float* __restrict__ out) {
    double pos = acc[0] + 8192.0 * exp(10.0);
    out[0] = (float)log1p(acc[1] / pos);
}

extern "C" void kernel_launch(void* const* d_in, const int* in_sizes, int n_in,
                              void* d_out, int out_size, void* d_ws, size_t ws_size,
                              hipStream_t stream) {
    const float* zi = (const float*)d_in[0];
    const float* zj = (const float*)d_in[1];
    u8* nrm = (u8*)d_ws;                                      // [16384][512] fp8 = 8 MB
    double* acc = (double*)((char*)d_ws + (size_t)16384 * 512);

    nrm_kernel<<<4096, 256, 0, stream>>>(zi, zj, nrm, acc);
    dim3 grid(128, 64);   // x: 16384/128 n-tiles, y: 8192/128 m-tiles
    gemm_exp_reduce<<<grid, 256, 0, stream>>>(nrm, nrm, acc);
    finalize<<<1, 1, 0, stream>>>(acc, (float*)d_out);
}

// Round 3
// 187.471 us; speedup vs baseline: 1.3067x; 1.0022x over previous
//
#include <hip/hip_runtime.h>
#include <cstdint>
#include <cmath>

#define NROWS 8192
#define KDIM  512            // elements; also bytes/row in fp8
#define T_INV 10.0f

typedef int    i32x4  __attribute__((ext_vector_type(4)));
typedef int    i32x8  __attribute__((ext_vector_type(8)));
typedef float  f32x16 __attribute__((ext_vector_type(16)));
typedef unsigned char u8;

#define AS1(p) ((const __attribute__((address_space(1))) void*)(p))
#define AS3(p) ((__attribute__((address_space(3))) void*)(p))

// --- Kernel 1: row L2-normalize fp32 -> fp8 e4m3 (OCP, HW cvt), one wave/row.
// zi rows [0,8192), zj rows [8192,16384). Also zeroes the accumulators.
__global__ __launch_bounds__(256) void nrm_kernel(const float* __restrict__ zi,
                                                  const float* __restrict__ zj,
                                                  u8* __restrict__ out,
                                                  double* __restrict__ acc) {
    if (blockIdx.x == 0 && threadIdx.x == 0) { acc[0] = 0.0; acc[1] = 0.0; }
    const int wave = threadIdx.x >> 6;
    const int lane = threadIdx.x & 63;
    const int row  = blockIdx.x * 4 + wave;            // 0..16383
    const float* src = (row < NROWS) ? zi + (size_t)row * KDIM
                                     : zj + (size_t)(row - NROWS) * KDIM;
    float4 a = ((const float4*)src)[lane];        // elements 4*lane .. 4*lane+3
    float4 b = ((const float4*)src)[lane + 64];   // elements 4*(lane+64) ..
    float ss = a.x*a.x + a.y*a.y + a.z*a.z + a.w*a.w
             + b.x*b.x + b.y*b.y + b.z*b.z + b.w*b.w;
    #pragma unroll
    for (int off = 32; off >= 1; off >>= 1) ss += __shfl_xor(ss, off, 64);
    const float inv = 1.0f / fmaxf(sqrtf(ss), 1e-12f);
    int p0 = 0, p1 = 0;
    p0 = __builtin_amdgcn_cvt_pk_fp8_f32(a.x * inv, a.y * inv, p0, false); // bytes 0,1
    p0 = __builtin_amdgcn_cvt_pk_fp8_f32(a.z * inv, a.w * inv, p0, true);  // bytes 2,3
    p1 = __builtin_amdgcn_cvt_pk_fp8_f32(b.x * inv, b.y * inv, p1, false);
    p1 = __builtin_amdgcn_cvt_pk_fp8_f32(b.z * inv, b.w * inv, p1, true);
    int* dst = (int*)(out + (size_t)row * KDIM);
    dst[lane]      = p0;   // bytes 4*lane..4*lane+3  == elements 4*lane..
    dst[lane + 64] = p1;
}

// --- Kernel 2: fused MX-fp8 A*B^T -> exp(10*dot) -> global sum.
// A = normalized zi [8192][512] fp8; B = normalized [16384][512] (zi then zj).
// Block = 128x128 tile, 4 waves in 2x2, each wave 64x64 via 2x2 of 32x32x64 frags.
// LDS layout is XOR-swizzled at 16B-chunk granularity to kill ds_read_b128 bank
// conflicts: within each 32-row operand-tile region (2048 B), global chunk
// (r, b) (r=row 0..31, b=16B-chunk 0..3 of the 64B k-slice) lives at position
// p = r*4 + (b ^ ((r>>1)&3)). Fragment read (chunks b=2q,2q+1 at row r) then
// covers all 8 bank groups evenly (conflict-free); staging inverse is
// b = (lane&3) ^ ((lane>>3)&3), still 64B-coalesced in global.
// Diagonal elements of the pos region are SKIPPED (added exactly in finalize).
__global__ __launch_bounds__(256) void gemm_exp_reduce(const u8* __restrict__ A,
                                                       const u8* __restrict__ B,
                                                       double* __restrict__ acc) {
    __shared__ u8 lA[128 * 64];   // 8 KB = 4 operand-tile regions of 2048 B
    __shared__ u8 lB[128 * 64];   // 8 KB
    __shared__ float red[4];

    const int tid  = threadIdx.x;
    const int lane = tid & 63;
    const int wave = tid >> 6;
    const int m0   = blockIdx.y * 128;
    const int n0   = blockIdx.x * 128;
    const int wm   = (wave >> 1) * 64;
    const int wn   = (wave & 1) * 64;

    f32x16 accf[2][2];
    #pragma unroll
    for (int i = 0; i < 2; ++i)
        #pragma unroll
        for (int j = 0; j < 2; ++j)
            #pragma unroll
            for (int r = 0; r < 16; ++r)
                accf[i][j][r] = 0.f;

    // staging: wave w stages rows w*32..+31 into region w*2048; instruction c
    // writes LDS [w*2048 + c*1024 + lane*16]; lane's global source is
    // row = w*32 + c*16 + (lane>>2), chunk b = (lane&3) ^ ((lane>>3)&3).
    const int bsw = (lane & 3) ^ ((lane >> 3) & 3);
    const u8* gA0 = A + (size_t)(m0 + wave * 32 + (lane >> 2)) * KDIM + bsw * 16;
    const u8* gB0 = B + (size_t)(n0 + wave * 32 + (lane >> 2)) * KDIM + bsw * 16;
    u8* lAd = &lA[wave * 2048 + lane * 16];
    u8* lBd = &lB[wave * 2048 + lane * 16];

    // fragment read: lane holds row r=lane&31, k-half q=lane>>5 (chunks 2q,2q+1)
    const int r_  = lane & 31;
    const int q_  = lane >> 5;
    const int p16 = (r_ * 4 + ((2 * q_) ^ ((r_ >> 1) & 3))) * 16;  // chunk 2q pos
    const int aTile0 = (wave >> 1) * 2;   // A tiles aTile0, aTile0+1
    const int bTile0 = (wave & 1) * 2;    // B tiles bTile0, bTile0+1

    for (int k0 = 0; k0 < KDIM; k0 += 64) {
        __syncthreads();   // previous iteration's ds_reads done before overwrite
        #pragma unroll
        for (int c = 0; c < 2; ++c) {
            __builtin_amdgcn_global_load_lds(AS1(gA0 + k0 + (size_t)c * 16 * KDIM),
                                             AS3(lAd + c * 1024), 16, 0, 0);
            __builtin_amdgcn_global_load_lds(AS1(gB0 + k0 + (size_t)c * 16 * KDIM),
                                             AS3(lBd + c * 1024), 16, 0, 0);
        }
        __syncthreads();   // vmcnt drain + barrier: tiles ready

        i32x8 af[2], bfr[2];
        #pragma unroll
        for (int mi = 0; mi < 2; ++mi) {
            const int off = (aTile0 + mi) * 2048 + p16;
            i32x4 lo = *(const i32x4*)&lA[off];        // chunk 2q  (bytes kh..+15)
            i32x4 hi = *(const i32x4*)&lA[off ^ 16];   // chunk 2q+1 (bytes kh+16..)
            af[mi] = (i32x8){lo[0], lo[1], lo[2], lo[3], hi[0], hi[1], hi[2], hi[3]};
        }
        #pragma unroll
        for (int ni = 0; ni < 2; ++ni) {
            const int off = (bTile0 + ni) * 2048 + p16;
            i32x4 lo = *(const i32x4*)&lB[off];
            i32x4 hi = *(const i32x4*)&lB[off ^ 16];
            bfr[ni] = (i32x8){lo[0], lo[1], lo[2], lo[3], hi[0], hi[1], hi[2], hi[3]};
        }
        #pragma unroll
        for (int mi = 0; mi < 2; ++mi)
            #pragma unroll
            for (int ni = 0; ni < 2; ++ni)
                accf[mi][ni] = __builtin_amdgcn_mfma_scale_f32_32x32x64_f8f6f4(
                    af[mi], bfr[ni], accf[mi][ni],
                    0, 0,                 // cbsz=fp8(e4m3), blgp=fp8(e4m3)
                    0, 0x7f7f7f7f,        // scale_a: every byte = 2^0
                    0, 0x7f7f7f7f);       // scale_b
    }

    // epilogue: exp(10*dot), skipping pos-region diagonal (only in bx==by tiles)
    float part = 0.f;
    const bool diagblk = (blockIdx.x == (unsigned)blockIdx.y);  // implies pos region
    if (diagblk) {
        #pragma unroll
        for (int mi = 0; mi < 2; ++mi)
            #pragma unroll
            for (int ni = 0; ni < 2; ++ni)
                #pragma unroll
                for (int r = 0; r < 16; ++r) {
                    // C/D 32x32: col=lane&31, row=(r&3)+8*(r>>2)+4*(lane>>5)
                    int rr = wm + mi * 32 + ((r & 3) + 8 * (r >> 2) + 4 * (lane >> 5));
                    int cc = wn + ni * 32 + (lane & 31);
                    if (rr != cc) part += __expf(accf[mi][ni][r] * T_INV);
                }
    } else {
        #pragma unroll
        for (int mi = 0; mi < 2; ++mi)
            #pragma unroll
            for (int ni = 0; ni < 2; ++ni)
                #pragma unroll
                for (int r = 0; r < 16; ++r)
                    part += __expf(accf[mi][ni][r] * T_INV);
    }

    #pragma unroll
    for (int off = 32; off >= 1; off >>= 1) part += __shfl_xor(part, off, 64);
    if (lane == 0) red[wave] = part;
    __syncthreads();
    if (tid == 0) {
        double s = (double)red[0] + (double)red[1] + (double)red[2] + (double)red[3];
        atomicAdd(&acc[(blockIdx.x < 64) ? 0 : 1], s);   // n-tile in zi region -> pos
    }
}

// --- Kernel 3: loss = log1p(neg / pos), pos += exact diagonal 8192*e^10 ---
__global__ void finalize(const double* __restrict__ acc, float* __restrict__ out) {
    double pos = acc[0] + 8192.0 * exp(10.0);
    out[0] = (float)log1p(acc[1] / pos);
}

extern "C" void kernel_launch(void* const* d_in, const int* in_sizes, int n_in,
                              void* d_out, int out_size, void* d_ws, size_t ws_size,
                              hipStream_t stream) {
    const float* zi = (const float*)d_in[0];
    const float* zj = (const float*)d_in[1];
    u8* nrm = (u8*)d_ws;                                      // [16384][512] fp8 = 8 MB
    double* acc = (double*)((char*)d_ws + (size_t)16384 * 512);

    nrm_kernel<<<4096, 256, 0, stream>>>(zi, zj, nrm, acc);
    dim3 grid(128, 64);   // x: 16384/128 n-tiles, y: 8192/128 m-tiles
    gemm_exp_reduce<<<grid, 256, 0, stream>>>(nrm, nrm, acc);
    finalize<<<1, 1, 0, stream>>>(acc, (float*)d_out);
}